// Round 5
// baseline (429.814 us; speedup 1.0000x reference)
//
#include <hip/hip_runtime.h>
#include <hip/hip_bf16.h>

typedef __hip_bfloat16 bf16;

static constexpr int kB = 4096;     // batch
static constexpr float kEPS = 1e-5f;

__device__ __forceinline__ float cvt(float v) { return v; }
__device__ __forceinline__ float cvt(bf16 v)  { return __bfloat162float(v); }

// ---------------------------------------------------------------------------
// Inline dtype detect (PROVEN predicate). fp32 misread as bf16 has random
// exponent fields -> |v|>2 or NaN within 64 elements. True-bf16 x is uniform
// [0,1). Returns 1 -> fp32, 0 -> bf16.
// ---------------------------------------------------------------------------
__device__ __forceinline__ int detect_dtype(const void* __restrict__ x) {
    const bf16* p = (const bf16*)x;
    int isf32 = 0;
    for (int i = 0; i < 64; ++i) {
        float v = __bfloat162float(p[i]);
        if (!(fabsf(v) <= 2.0f)) isf32 = 1;  // catches NaN too
    }
    return isf32;
}

// ---------------------------------------------------------------------------
// Foveate v3: phase-1 pooling restructured for low per-iteration overhead.
//  - thread -> fixed column (ox = tid&63, active < 56): gx + x-bounds
//    predicates are LOOP-INVARIANT (computed once, not per output).
//  - rows -> tid>>6 (4 rows/pass): gy is WAVE-UNIFORM -> row-bounds checks
//    are scalar branches; fully-OOB rows skip all loads.
//  - index math is shift/mask only (no integer division in the hot loop).
// Numerics bit-identical to the proven kernel: same add order
// ((v00+v01)+v10)+v11, same zero-for-OOB semantics, same downstream phases.
// LDS 16 KB -> 8 blocks/CU.
// ---------------------------------------------------------------------------
template <typename T>
__device__ void foveate_impl(const T* __restrict__ x, const T* __restrict__ loc,
                             float* __restrict__ phi, float* __restrict__ L1,
                             float* __restrict__ L2) {
    int b = blockIdx.x;
    float lx = cvt(loc[2 * b + 0]);
    float ly = cvt(loc[2 * b + 1]);
    // exact replication of (0.5*((loc+1)*128)).astype(int32); ops exact in fp32
    int cx = (int)(0.5f * ((lx + 1.0f) * 128.0f));
    int cy = (int)(0.5f * ((ly + 1.0f) * 128.0f));
    const T* img = x + (size_t)b * 16384;
    float* ph = phi + (size_t)b * 784;

    int by0 = cy - 56, bx0 = cx - 56;

    // ---- phase 1: 2x2 pool folded into the global read -> L1(56x56) ------
    {
        int ox   = threadIdx.x & 63;     // fixed column; active when < 56
        int orow = threadIdx.x >> 6;     // 0..3, wave-uniform
        int gx0 = bx0 + 2 * ox, gx1 = gx0 + 1;
        bool px0 = (unsigned)gx0 < 128u;           // loop-invariant
        bool px1 = (unsigned)gx1 < 128u;
        if (ox < 56) {
            for (int oy = orow; oy < 56; oy += 4) {
                int gy0 = by0 + 2 * oy, gy1 = gy0 + 1;
                float v00 = 0.f, v01 = 0.f, v10 = 0.f, v11 = 0.f;
                if ((unsigned)gy0 < 128u) {        // wave-uniform branch
                    const T* r = img + gy0 * 128;
                    if (px0) v00 = cvt(r[gx0]);
                    if (px1) v01 = cvt(r[gx1]);
                }
                if ((unsigned)gy1 < 128u) {        // wave-uniform branch
                    const T* r = img + gy1 * 128;
                    if (px0) v10 = cvt(r[gx0]);
                    if (px1) v11 = cvt(r[gx1]);
                }
                L1[oy * 57 + ox] = ((v00 + v01) + v10) + v11;  // proven order
            }
        }
    }
    __syncthreads();

    // ---- phase 2: j0 raw center (global, L1-cache hot) + j1 from L1 ------
    for (int i = threadIdx.x; i < 196; i += 256) {
        int r = i / 14, c = i % 14;
        int gy = cy - 7 + r, gx = cx - 7 + c;
        float v = ((unsigned)gy < 128u && (unsigned)gx < 128u) ? cvt(img[gy * 128 + gx]) : 0.f;
        ph[i] = v;
        ph[196 + i] = L1[(21 + r) * 57 + 21 + c] * 0.25f;
    }
    // ---- phase 3: L2(28x28) pool from L1 ---------------------------------
    for (int i = threadIdx.x; i < 784; i += 256) {
        int oy = i / 28, ox = i % 28;
        const float* p = L1 + (2 * oy) * 57 + 2 * ox;
        L2[oy * 29 + ox] = p[0] + p[1] + p[57] + p[58];
    }
    __syncthreads();

    // ---- phase 4: j2 from L2, j3 = pool(L2) ------------------------------
    for (int i = threadIdx.x; i < 196; i += 256) {
        int r = i / 14, c = i % 14;
        ph[392 + i] = L2[(7 + r) * 29 + 7 + c] * 0.0625f;
        const float* p = L2 + (2 * r) * 29 + 2 * c;
        ph[588 + i] = (p[0] + p[1] + p[29] + p[30]) * 0.015625f;
    }
}

__global__ __launch_bounds__(256) void foveate_kernel(const void* __restrict__ x,
                                                      const void* __restrict__ loc,
                                                      float* __restrict__ phi,
                                                      int* __restrict__ flag) {
    __shared__ float L1[56 * 57];
    __shared__ float L2[28 * 29];
    int isf32 = detect_dtype(x);                 // uniform across all blocks
    if (blockIdx.x == 0 && threadIdx.x == 0) *flag = isf32;
    if (isf32) foveate_impl<float>((const float*)x, (const float*)loc, phi, L1, L2);
    else       foveate_impl<bf16>((const bf16*)x, (const bf16*)loc, phi, L1, L2);
}

// ---------------------------------------------------------------------------
// gemm1 (PROVEN tiling, verbatim): C[4096,128] = phi @ W1 + b1, fused stats.
// BM=64, BN=32, BK=16, 256 threads, 4x2 micro-tile, register prefetch.
// ---------------------------------------------------------------------------
template <typename T>
__device__ void gemm1_impl(const float* __restrict__ A, const T* __restrict__ W,
                           const T* __restrict__ bias, float* __restrict__ C,
                           float* __restrict__ part_s, float* __restrict__ part_q,
                           float* As /*16x68*/, float* Bs /*16x32*/,
                           int row0, int n0, int by) {
    int tid = threadIdx.x;
    int tx = tid & 15, ty = tid >> 4;            // micro: rows ty*4..+3, cols tx*2..+1

    float acc[4][2] = {};
    int am = tid >> 2;                            // 0..63 : A row within tile
    int ak = (tid & 3) << 2;                      // 0,4,8,12
    int bn = tid & 31;                            // W col within tile
    int bk = tid >> 5;                            // 0..7 -> k rows bk, bk+8

    const float* Aptr = A + (size_t)(row0 + am) * 784 + ak;
    float4 av = *(const float4*)Aptr;
    float b0 = cvt(W[(size_t)bk * 128 + n0 + bn]);
    float b1 = cvt(W[(size_t)(bk + 8) * 128 + n0 + bn]);

    for (int t = 0; t < 49; ++t) {
        As[(ak + 0) * 68 + am] = av.x; As[(ak + 1) * 68 + am] = av.y;
        As[(ak + 2) * 68 + am] = av.z; As[(ak + 3) * 68 + am] = av.w;
        Bs[bk * 32 + bn] = b0; Bs[(bk + 8) * 32 + bn] = b1;
        __syncthreads();
        if (t < 48) {
            int k0 = (t + 1) << 4;
            av = *(const float4*)(Aptr + k0);
            b0 = cvt(W[(size_t)(k0 + bk) * 128 + n0 + bn]);
            b1 = cvt(W[(size_t)(k0 + bk + 8) * 128 + n0 + bn]);
        }
#pragma unroll
        for (int k = 0; k < 16; ++k) {
            float4 a  = *(const float4*)&As[k * 68 + ty * 4];
            float2 bb = *(const float2*)&Bs[k * 32 + tx * 2];
            acc[0][0] = fmaf(a.x, bb.x, acc[0][0]); acc[0][1] = fmaf(a.x, bb.y, acc[0][1]);
            acc[1][0] = fmaf(a.y, bb.x, acc[1][0]); acc[1][1] = fmaf(a.y, bb.y, acc[1][1]);
            acc[2][0] = fmaf(a.z, bb.x, acc[2][0]); acc[2][1] = fmaf(a.z, bb.y, acc[2][1]);
            acc[3][0] = fmaf(a.w, bb.x, acc[3][0]); acc[3][1] = fmaf(a.w, bb.y, acc[3][1]);
        }
        __syncthreads();
    }

    float bv0 = cvt(bias[n0 + tx * 2]);
    float bv1 = cvt(bias[n0 + tx * 2 + 1]);
    float cs0 = 0.f, cs1 = 0.f, cq0 = 0.f, cq1 = 0.f;
#pragma unroll
    for (int i = 0; i < 4; ++i) {
        float v0 = acc[i][0] + bv0, v1 = acc[i][1] + bv1;
        float2 o; o.x = v0; o.y = v1;
        *(float2*)(C + (size_t)(row0 + ty * 4 + i) * 128 + n0 + tx * 2) = o;
        cs0 += v0; cq0 += v0 * v0; cs1 += v1; cq1 += v1 * v1;
    }
    __syncthreads();  // tiles dead; reuse as reduction scratch
    As[ty * 32 + tx * 2]     = cs0; As[ty * 32 + tx * 2 + 1] = cs1;
    Bs[ty * 32 + tx * 2]     = cq0; Bs[ty * 32 + tx * 2 + 1] = cq1;
    __syncthreads();
    if (tid < 32) {
        float s = 0.f, q = 0.f;
#pragma unroll
        for (int p = 0; p < 16; ++p) { s += As[p * 32 + tid]; q += Bs[p * 32 + tid]; }
        part_s[(size_t)by * 128 + n0 + tid] = s;
        part_q[(size_t)by * 128 + n0 + tid] = q;
    }
}

// ---------------------------------------------------------------------------
// Where layer 1 (K=2) fused with partial stats (proven, verbatim; wb param).
// ---------------------------------------------------------------------------
template <typename T>
__device__ void where1_impl(const T* __restrict__ loc, const T* __restrict__ W,
                            const T* __restrict__ bias, float* __restrict__ q1,
                            float* __restrict__ part_s, float* __restrict__ part_q,
                            float* redS, float* redQ, int wb) {
    int c    = threadIdx.x & 127;
    int rsub = threadIdx.x >> 7;   // 0..1
    int rbase = wb * 64;
    float w0 = cvt(W[c]), w1 = cvt(W[128 + c]), bv = cvt(bias[c]);
    float s = 0.f, q = 0.f;
#pragma unroll
    for (int p = 0; p < 32; ++p) {
        int r = rbase + rsub + 2 * p;
        float v = fmaf(cvt(loc[2 * r]), w0, fmaf(cvt(loc[2 * r + 1]), w1, bv));
        q1[(size_t)r * 128 + c] = v;
        s += v; q += v * v;
    }
    redS[threadIdx.x] = s; redQ[threadIdx.x] = q;
    __syncthreads();
    if (threadIdx.x < 128) {
        part_s[(size_t)wb * 128 + c] = redS[c] + redS[c + 128];
        part_q[(size_t)wb * 128 + c] = redQ[c] + redQ[c + 128];
    }
}

// ---------------------------------------------------------------------------
// Merged launch: blocks 0..63 run where-L1 (tiny, no phi dependency); blocks
// 64..319 run the what-path gemm1. All 320 blocks co-resident in one wave.
// ---------------------------------------------------------------------------
__global__ __launch_bounds__(256) void gemm1_where1(
        const float* __restrict__ phi, const void* __restrict__ wW1,
        const void* __restrict__ wb1, float* __restrict__ h1,
        float* __restrict__ pS1, float* __restrict__ pQ1,
        const void* __restrict__ loc, const void* __restrict__ hW1,
        const void* __restrict__ hb1, float* __restrict__ q1,
        float* __restrict__ pSw1, float* __restrict__ pQw1,
        const int* __restrict__ flag) {
    __shared__ __align__(16) float As[16 * 68];
    __shared__ __align__(16) float Bs[16 * 32];
    if (blockIdx.x < 64) {
        int wb = blockIdx.x;
        if (*flag) where1_impl<float>((const float*)loc, (const float*)hW1,
                                      (const float*)hb1, q1, pSw1, pQw1, As, Bs, wb);
        else       where1_impl<bf16>((const bf16*)loc, (const bf16*)hW1,
                                     (const bf16*)hb1, q1, pSw1, pQw1, As, Bs, wb);
    } else {
        int g = blockIdx.x - 64;
        int n0 = (g & 3) * 32, by = g >> 2, row0 = by * 64;
        if (*flag) gemm1_impl<float>(phi, (const float*)wW1, (const float*)wb1,
                                     h1, pS1, pQ1, As, Bs, row0, n0, by);
        else       gemm1_impl<bf16>(phi, (const bf16*)wW1, (const bf16*)wb1,
                                    h1, pS1, pQ1, As, Bs, row0, n0, by);
    }
}

// ---------------------------------------------------------------------------
// gemm2/gemm3 merged (grid.z selects path), WITH INLINE layer-1 stat
// finalization in the prologue (bit-identical double-precision reduction).
// Body: C[4096,256] = relu(BN(A)) @ W + b. BM=BN=64, BK=16, 4x4 micro,
// register prefetch. Epilogue: bias + partial stats (proven, verbatim).
// ---------------------------------------------------------------------------
template <typename T>
__device__ void gemm2_impl(const float* __restrict__ A, const T* __restrict__ W,
                           const T* __restrict__ bias,
                           const float* __restrict__ pS, const float* __restrict__ pQ,
                           const T* __restrict__ g1v, const T* __restrict__ be1v,
                           float* __restrict__ C, float* __restrict__ part_s,
                           float* __restrict__ part_q,
                           float* As, float* Bs, float* stS) {
    int tid = threadIdx.x;
    // ---- prologue: finalize layer-1 stats (identical math to old kernel) --
    if (tid < 128) {
        double s = 0.0, q = 0.0;
        for (int p = 0; p < 64; ++p) {
            s += (double)pS[p * 128 + tid];
            q += (double)pQ[p * 128 + tid];
        }
        double mean = s / 4096.0;
        double var  = q / 4096.0 - mean * mean;
        float rstd  = (float)(1.0 / sqrt(var + (double)kEPS));
        float scale = rstd * cvt(g1v[tid]);
        stS[tid]       = scale;
        stS[128 + tid] = cvt(be1v[tid]) - (float)mean * scale;
    }
    __syncthreads();

    int tx = tid & 15, ty = tid >> 4;
    int row0 = blockIdx.y * 64, n0 = blockIdx.x * 64;

    float acc[4][4] = {};
    int am = tid >> 2, ak = (tid & 3) << 2;
    int bn = tid & 63, bk0 = tid >> 6;

    const float* Aptr = A + (size_t)(row0 + am) * 128 + ak;
    float4 av = *(const float4*)Aptr;
    float4 sc = *(const float4*)(stS + ak);
    float4 sh = *(const float4*)(stS + 128 + ak);
    float bv[4];
#pragma unroll
    for (int p = 0; p < 4; ++p) bv[p] = cvt(W[(size_t)(bk0 + 4 * p) * 256 + n0 + bn]);

    for (int t = 0; t < 8; ++t) {
        As[(ak + 0) * 68 + am] = fmaxf(fmaf(av.x, sc.x, sh.x), 0.f);
        As[(ak + 1) * 68 + am] = fmaxf(fmaf(av.y, sc.y, sh.y), 0.f);
        As[(ak + 2) * 68 + am] = fmaxf(fmaf(av.z, sc.z, sh.z), 0.f);
        As[(ak + 3) * 68 + am] = fmaxf(fmaf(av.w, sc.w, sh.w), 0.f);
#pragma unroll
        for (int p = 0; p < 4; ++p) Bs[(bk0 + 4 * p) * 64 + bn] = bv[p];
        __syncthreads();
        if (t < 7) {
            int k0 = (t + 1) << 4;
            av = *(const float4*)(Aptr + k0);
            sc = *(const float4*)(stS + k0 + ak);
            sh = *(const float4*)(stS + 128 + k0 + ak);
#pragma unroll
            for (int p = 0; p < 4; ++p) bv[p] = cvt(W[(size_t)(k0 + bk0 + 4 * p) * 256 + n0 + bn]);
        }
#pragma unroll
        for (int k = 0; k < 16; ++k) {
            float4 a = *(const float4*)&As[k * 68 + ty * 4];
            float4 b = *(const float4*)&Bs[k * 64 + tx * 4];
            acc[0][0] = fmaf(a.x, b.x, acc[0][0]); acc[0][1] = fmaf(a.x, b.y, acc[0][1]);
            acc[0][2] = fmaf(a.x, b.z, acc[0][2]); acc[0][3] = fmaf(a.x, b.w, acc[0][3]);
            acc[1][0] = fmaf(a.y, b.x, acc[1][0]); acc[1][1] = fmaf(a.y, b.y, acc[1][1]);
            acc[1][2] = fmaf(a.y, b.z, acc[1][2]); acc[1][3] = fmaf(a.y, b.w, acc[1][3]);
            acc[2][0] = fmaf(a.z, b.x, acc[2][0]); acc[2][1] = fmaf(a.z, b.y, acc[2][1]);
            acc[2][2] = fmaf(a.z, b.z, acc[2][2]); acc[2][3] = fmaf(a.z, b.w, acc[2][3]);
            acc[3][0] = fmaf(a.w, b.x, acc[3][0]); acc[3][1] = fmaf(a.w, b.y, acc[3][1]);
            acc[3][2] = fmaf(a.w, b.z, acc[3][2]); acc[3][3] = fmaf(a.w, b.w, acc[3][3]);
        }
        __syncthreads();
    }

    float bb[4];
#pragma unroll
    for (int j = 0; j < 4; ++j) bb[j] = cvt(bias[n0 + tx * 4 + j]);
    float cs[4] = {}, cq[4] = {};
#pragma unroll
    for (int i = 0; i < 4; ++i) {
        float v0 = acc[i][0] + bb[0], v1 = acc[i][1] + bb[1];
        float v2 = acc[i][2] + bb[2], v3 = acc[i][3] + bb[3];
        float4 o; o.x = v0; o.y = v1; o.z = v2; o.w = v3;
        cs[0] += v0; cs[1] += v1; cs[2] += v2; cs[3] += v3;
        cq[0] += v0 * v0; cq[1] += v1 * v1; cq[2] += v2 * v2; cq[3] += v3 * v3;
        *(float4*)(C + (size_t)(row0 + ty * 4 + i) * 256 + n0 + tx * 4) = o;
    }
    __syncthreads();
#pragma unroll
    for (int j = 0; j < 4; ++j) {
        As[ty * 64 + tx * 4 + j] = cs[j];
        Bs[ty * 64 + tx * 4 + j] = cq[j];
    }
    __syncthreads();
    if (tid < 64) {
        float s = 0.f, q = 0.f;
#pragma unroll
        for (int p = 0; p < 16; ++p) { s += As[p * 64 + tid]; q += Bs[p * 64 + tid]; }
        part_s[(size_t)blockIdx.y * 256 + n0 + tid] = s;
        part_q[(size_t)blockIdx.y * 256 + n0 + tid] = q;
    }
}

__global__ __launch_bounds__(256) void gemm23_fused(
        const float* __restrict__ h1, const float* __restrict__ q1,
        const void* __restrict__ wW2, const void* __restrict__ wb2,
        const void* __restrict__ hW2, const void* __restrict__ hb2,
        const float* __restrict__ pS1, const float* __restrict__ pQ1,
        const void* __restrict__ wg1, const void* __restrict__ wbe1,
        const float* __restrict__ pSw1, const float* __restrict__ pQw1,
        const void* __restrict__ hg1, const void* __restrict__ hbe1,
        float* __restrict__ h2, float* __restrict__ q2,
        float* __restrict__ pS2, float* __restrict__ pQ2,
        float* __restrict__ pSw2, float* __restrict__ pQw2,
        const int* __restrict__ flag) {
    __shared__ __align__(16) float As[16 * 68];
    __shared__ __align__(16) float Bs[16 * 64];
    __shared__ __align__(16) float stS[256];
    const float* A; const void* W; const void* bias;
    const float* pS; const float* pQ; const void* g1v; const void* be1v;
    float* C; float* ps; float* pq;
    if (blockIdx.z == 0) {
        A = h1; W = wW2; bias = wb2; pS = pS1;  pQ = pQ1;  g1v = wg1; be1v = wbe1;
        C = h2; ps = pS2;  pq = pQ2;
    } else {
        A = q1; W = hW2; bias = hb2; pS = pSw1; pQ = pQw1; g1v = hg1; be1v = hbe1;
        C = q2; ps = pSw2; pq = pQw2;
    }
    if (*flag) gemm2_impl<float>(A, (const float*)W, (const float*)bias, pS, pQ,
                                 (const float*)g1v, (const float*)be1v, C, ps, pq, As, Bs, stS);
    else       gemm2_impl<bf16>(A, (const bf16*)W, (const bf16*)bias, pS, pQ,
                                (const bf16*)g1v, (const bf16*)be1v, C, ps, pq, As, Bs, stS);
}

// ---------------------------------------------------------------------------
// Final: out = relu( BN(h2) + BN(q2) ). Layer-2 stats finalized in-register
// from the partials (thread c only touches column c; period-256 grid stride).
// ---------------------------------------------------------------------------
template <typename T>
__device__ void final_impl(const float* __restrict__ h2, const float* __restrict__ q2,
                           const float* __restrict__ pS2, const float* __restrict__ pQ2,
                           const float* __restrict__ pSw2, const float* __restrict__ pQw2,
                           const T* __restrict__ g2, const T* __restrict__ be2,
                           const T* __restrict__ gw2, const T* __restrict__ bew2,
                           T* __restrict__ out) {
    int c = threadIdx.x;  // 256 threads, N=256
    double s = 0.0, q = 0.0, sw = 0.0, qw = 0.0;
    for (int p = 0; p < 64; ++p) {
        s  += (double)pS2[p * 256 + c];  q  += (double)pQ2[p * 256 + c];
        sw += (double)pSw2[p * 256 + c]; qw += (double)pQw2[p * 256 + c];
    }
    double mH = s / 4096.0,  vH = q / 4096.0 - mH * mH;
    double mQ = sw / 4096.0, vQ = qw / 4096.0 - mQ * mQ;
    float rH = (float)(1.0 / sqrt(vH + (double)kEPS));
    float rQ = (float)(1.0 / sqrt(vQ + (double)kEPS));
    float aH = rH * cvt(g2[c]);  float bH = cvt(be2[c])  - (float)mH * aH;
    float aQ = rQ * cvt(gw2[c]); float bQ = cvt(bew2[c]) - (float)mQ * aQ;

    for (int idx = blockIdx.x * 256 + c; idx < kB * 256; idx += 256 * 256) {
        float v = fmaxf(fmaf(h2[idx], aH, bH) + fmaf(q2[idx], aQ, bQ), 0.f);
        out[idx] = (T)v;
    }
}

__global__ __launch_bounds__(256) void final_kernel(
        const float* __restrict__ h2, const float* __restrict__ q2,
        const float* __restrict__ pS2, const float* __restrict__ pQ2,
        const float* __restrict__ pSw2, const float* __restrict__ pQw2,
        const void* __restrict__ g2, const void* __restrict__ be2,
        const void* __restrict__ gw2, const void* __restrict__ bew2,
        void* __restrict__ out, const int* __restrict__ flag) {
    if (*flag) final_impl<float>(h2, q2, pS2, pQ2, pSw2, pQw2, (const float*)g2, (const float*)be2,
                                 (const float*)gw2, (const float*)bew2, (float*)out);
    else       final_impl<bf16>(h2, q2, pS2, pQ2, pSw2, pQw2, (const bf16*)g2, (const bf16*)be2,
                                (const bf16*)gw2, (const bf16*)bew2, (bf16*)out);
}

// ---------------------------------------------------------------------------
extern "C" void kernel_launch(void* const* d_in, const int* in_sizes, int n_in,
                              void* d_out, int out_size, void* d_ws, size_t ws_size,
                              hipStream_t stream) {
    (void)in_sizes; (void)n_in; (void)out_size; (void)ws_size;
    const void* x    = d_in[0];
    const void* loc  = d_in[1];
    const void* wW1  = d_in[2];   // (784,128)
    const void* wb1  = d_in[3];
    const void* wg1  = d_in[4];
    const void* wbe1 = d_in[5];
    const void* wW2  = d_in[6];   // (128,256)
    const void* wb2  = d_in[7];
    const void* wg2  = d_in[8];
    const void* wbe2 = d_in[9];
    const void* hW1  = d_in[10];  // (2,128)
    const void* hb1  = d_in[11];
    const void* hg1  = d_in[12];
    const void* hbe1 = d_in[13];
    const void* hW2  = d_in[14];  // (128,256)
    const void* hb2  = d_in[15];
    const void* hg2  = d_in[16];
    const void* hbe2 = d_in[17];

    int*   flag = (int*)d_ws;
    float* ws   = (float*)d_ws + 16;            // 64B-aligned scratch
    float* phi  = ws;                           // 4096*784
    float* h1   = phi + (size_t)kB * 784;       // 4096*128
    float* q1   = h1  + (size_t)kB * 128;       // 4096*128
    float* h2   = q1  + (size_t)kB * 128;       // 4096*256
    float* q2   = h2  + (size_t)kB * 256;       // 4096*256
    float* pS1  = q2  + (size_t)kB * 256;       // 64*128
    float* pQ1  = pS1 + 8192;                   // 64*128
    float* pSw1 = pQ1 + 8192;                   // 64*128
    float* pQw1 = pSw1 + 8192;                  // 64*128
    // layer-2 partials overlay phi (phi is dead after gemm1)
    float* pS2  = phi;                          // 64*256
    float* pQ2  = pS2 + 16384;
    float* pSw2 = pQ2 + 16384;
    float* pQw2 = pSw2 + 16384;

    // 1) foveation (one block per image; publishes dtype flag)
    foveate_kernel<<<4096, 256, 0, stream>>>(x, loc, phi, flag);

    // 2) what-path layer-1 GEMM (blocks 64..319) + where-L1 (blocks 0..63)
    gemm1_where1<<<320, 256, 0, stream>>>(phi, wW1, wb1, h1, pS1, pQ1,
                                          loc, hW1, hb1, q1, pSw1, pQw1, flag);

    // 3) layer-2 GEMMs with inline layer-1 stat finalization + fused BN/relu
    gemm23_fused<<<dim3(4, 64, 2), 256, 0, stream>>>(
        h1, q1, wW2, wb2, hW2, hb2,
        pS1, pQ1, wg1, wbe1, pSw1, pQw1, hg1, hbe1,
        h2, q2, pS2, pQ2, pSw2, pQw2, flag);

    // 4) finalize layer-2 stats in-register + combine + relu + cast
    final_kernel<<<256, 256, 0, stream>>>(h2, q2, pS2, pQ2, pSw2, pQw2,
                                          wg2, wbe2, hg2, hbe2, d_out, flag);
}